// Round 1
// baseline (884.528 us; speedup 1.0000x reference)
//
#include <hip/hip_runtime.h>
#include <math.h>

#define NSWEEP 7

// ---------------------------------------------------------------------------
// Kernel 1: partial max-pooled outer products.
// Grid = B*G blocks, 256 threads. Each block handles 4096/G points of one
// batch, staging 64-point tiles (64x64 f32 = 16KB) in LDS. Thread t owns the
// 4x4 output block (i0..i0+3, j0..j0+3) -> per point: 2x ds_read_b128 + 16 fmul/fmax.
// ---------------------------------------------------------------------------
__global__ __launch_bounds__(256) void pool_kernel(const float* __restrict__ x,
                                                   float* __restrict__ part,
                                                   int G) {
  __shared__ float xs[4096];
  const int t = threadIdx.x;
  const int blk = blockIdx.x;
  const int b = blk / G, g = blk % G;
  const int npb = 4096 / G;
  const int ntile = npb >> 6;
  const int n0 = g * npb;
  const int i0 = (t >> 4) * 4;
  const int j0 = (t & 15) * 4;

  float mv[4][4];
#pragma unroll
  for (int a = 0; a < 4; ++a)
#pragma unroll
    for (int c = 0; c < 4; ++c) mv[a][c] = -INFINITY;

  const float4* src = reinterpret_cast<const float4*>(x + ((size_t)b * 4096 + n0) * 64);
  float4* xs4 = reinterpret_cast<float4*>(xs);

  for (int tile = 0; tile < ntile; ++tile) {
#pragma unroll
    for (int q = 0; q < 4; ++q) xs4[t + 256 * q] = src[(size_t)tile * 1024 + t + 256 * q];
    __syncthreads();
#pragma unroll 4
    for (int n = 0; n < 64; ++n) {
      const float4 vi = *reinterpret_cast<const float4*>(&xs[n * 64 + i0]);
      const float4 vj = *reinterpret_cast<const float4*>(&xs[n * 64 + j0]);
      const float fi[4] = {vi.x, vi.y, vi.z, vi.w};
      const float fj[4] = {vj.x, vj.y, vj.z, vj.w};
#pragma unroll
      for (int a = 0; a < 4; ++a)
#pragma unroll
        for (int c = 0; c < 4; ++c)
          mv[a][c] = fmaxf(mv[a][c], fi[a] * fj[c]);
    }
    __syncthreads();
  }

  // Stage result in LDS so the global write is coalesced.
#pragma unroll
  for (int a = 0; a < 4; ++a)
#pragma unroll
    for (int c = 0; c < 4; ++c)
      xs[(i0 + a) * 64 + (j0 + c)] = mv[a][c];
  __syncthreads();

  float* dst = part + ((size_t)b * G + g) * 4096;
#pragma unroll
  for (int q = 0; q < 16; ++q) dst[t + 256 * q] = xs[t + 256 * q];
}

// ---------------------------------------------------------------------------
// Kernel 2: per-batch symmetric eigendecomposition (parallel cyclic Jacobi),
// signed sqrt reconstruction, L2 normalization. One block (256 thr) per batch.
// LDS matrices padded to stride 65: bank(i,j) = (i + j) % 32 -> both row- and
// column-phase accesses are conflict-free.
// ---------------------------------------------------------------------------
__global__ __launch_bounds__(256) void eig_kernel(const float* __restrict__ part,
                                                  float* __restrict__ out,
                                                  int G) {
  __shared__ float A[64 * 65];
  __shared__ float Qm[64 * 65];
  __shared__ float W[64 * 65];
  __shared__ float cA[32], sA[32];
  __shared__ int pA[32], qA[32];
  __shared__ float gl[64];
  __shared__ float red[8];

  const int b = blockIdx.x;
  const int t = threadIdx.x;

  // ---- reduce partial maxima into A; init Q = I ----
#pragma unroll
  for (int u = 0; u < 16; ++u) {
    const int e = t + 256 * u;
    float m = -INFINITY;
    for (int g = 0; g < G; ++g)
      m = fmaxf(m, part[((size_t)b * G + g) * 4096 + e]);
    const int i = e >> 6, j = e & 63;
    A[i * 65 + j] = m;
    Qm[i * 65 + j] = (i == j) ? 1.0f : 0.0f;
  }
  __syncthreads();

  // ---- parallel Jacobi sweeps ----
  for (int sweep = 0; sweep < NSWEEP; ++sweep) {
    for (int r = 0; r < 63; ++r) {
      // Phase A: 32 rotations from the closed-form round-robin schedule.
      if (t < 32) {
        int p, q;
        if (t == 0) {
          p = 0;
          q = 1 + (62 + r) % 63;
        } else {
          p = 1 + (t - 1 + r) % 63;
          q = 1 + (62 - t + r) % 63;
        }
        const float app = A[p * 65 + p];
        const float aqq = A[q * 65 + q];
        const float apq = A[p * 65 + q];
        float c, s;
        if (fabsf(apq) < 1e-20f) {
          c = 1.0f; s = 0.0f;
        } else {
          const float tau = (aqq - app) / (2.0f * apq);
          float tt = 1.0f / (fabsf(tau) + sqrtf(1.0f + tau * tau));
          tt = copysignf(tt, tau);
          c = 1.0f / sqrtf(1.0f + tt * tt);
          s = tt * c;
        }
        pA[t] = p; qA[t] = q; cA[t] = c; sA[t] = s;
      }
      __syncthreads();

      // Phase B: row update A <- J^T A  (rows form a perfect matching: no races)
#pragma unroll
      for (int u = 0; u < 8; ++u) {
        const int item = t + 256 * u;
        const int k = item >> 6, j = item & 63;
        const int p = pA[k], q = qA[k];
        const float c = cA[k], s = sA[k];
        const float rp = A[p * 65 + j], rq = A[q * 65 + j];
        A[p * 65 + j] = c * rp - s * rq;
        A[q * 65 + j] = s * rp + c * rq;
      }
      __syncthreads();

      // Phase C: column update A <- A J, and eigenvector accumulation Q <- Q J
#pragma unroll
      for (int u = 0; u < 8; ++u) {
        const int item = t + 256 * u;
        const int k = item >> 6, i = item & 63;
        const int p = pA[k], q = qA[k];
        const float c = cA[k], s = sA[k];
        const float cp = A[i * 65 + p], cq = A[i * 65 + q];
        A[i * 65 + p] = c * cp - s * cq;
        A[i * 65 + q] = s * cp + c * cq;
      }
#pragma unroll
      for (int u = 0; u < 8; ++u) {
        const int item = t + 256 * u;
        const int k = item >> 6, i = item & 63;
        const int p = pA[k], q = qA[k];
        const float c = cA[k], s = sA[k];
        const float cp = Qm[i * 65 + p], cq = Qm[i * 65 + q];
        Qm[i * 65 + p] = c * cp - s * cq;
        Qm[i * 65 + q] = s * cp + c * cq;
      }
      __syncthreads();
    }
  }

  // ---- g(lambda) = sign(lambda)*sqrt(|lambda|) ----
  if (t < 64) {
    const float lam = A[t * 65 + t];
    gl[t] = copysignf(sqrtf(fabsf(lam)), lam);
  }
  __syncthreads();

  // ---- W = Q * diag(g) ----
#pragma unroll
  for (int u = 0; u < 16; ++u) {
    const int e = t + 256 * u;
    const int i = e >> 6, k = e & 63;
    W[i * 65 + k] = gl[k] * Qm[i * 65 + k];
  }
  __syncthreads();

  // ---- R = W * Q^T  (symmetric), accumulate sum of squares ----
  float rv[16];
  float ss = 0.0f;
#pragma unroll
  for (int u = 0; u < 16; ++u) {
    const int e = t + 256 * u;
    const int i = e >> 6, j = e & 63;
    float acc = 0.0f;
#pragma unroll 16
    for (int k = 0; k < 64; ++k)
      acc += W[i * 65 + k] * Qm[j * 65 + k];
    rv[u] = acc;
    ss += acc * acc;
  }

  // ---- block reduction of ss ----
#pragma unroll
  for (int off = 32; off > 0; off >>= 1) ss += __shfl_down(ss, off);
  if ((t & 63) == 0) red[t >> 6] = ss;
  __syncthreads();
  if (t == 0) {
    const float tot = red[0] + red[1] + red[2] + red[3];
    const float nrm = sqrtf(tot);
    red[0] = 1.0f / fmaxf(nrm, 1e-12f);
  }
  __syncthreads();
  const float rn = red[0];

#pragma unroll
  for (int u = 0; u < 16; ++u) {
    const int e = t + 256 * u;
    out[(size_t)b * 4096 + e] = rv[u] * rn;
  }
}

extern "C" void kernel_launch(void* const* d_in, const int* in_sizes, int n_in,
                              void* d_out, int out_size, void* d_ws, size_t ws_size,
                              hipStream_t stream) {
  const float* x = (const float*)d_in[0];
  float* out = (float*)d_out;
  float* part = (float*)d_ws;

  // Partial-max groups per batch; shrink if workspace is small (deterministic).
  int G = 16;
  while (G > 1 && (size_t)16 * G * 4096 * 4 > ws_size) G >>= 1;

  pool_kernel<<<dim3(16 * G), dim3(256), 0, stream>>>(x, part, G);
  eig_kernel<<<dim3(16), dim3(256), 0, stream>>>(part, out, G);
}

// Round 2
// 625.733 us; speedup vs baseline: 1.4136x; 1.4136x over previous
//
#include <hip/hip_runtime.h>
#include <math.h>

#define NSWEEP 8

// ---------------------------------------------------------------------------
// Kernel 1: partial max-pooled outer products (unchanged from R0).
// ---------------------------------------------------------------------------
__global__ __launch_bounds__(256) void pool_kernel(const float* __restrict__ x,
                                                   float* __restrict__ part,
                                                   int G) {
  __shared__ float xs[4096];
  const int t = threadIdx.x;
  const int blk = blockIdx.x;
  const int b = blk / G, g = blk % G;
  const int npb = 4096 / G;
  const int ntile = npb >> 6;
  const int n0 = g * npb;
  const int i0 = (t >> 4) * 4;
  const int j0 = (t & 15) * 4;

  float mv[4][4];
#pragma unroll
  for (int a = 0; a < 4; ++a)
#pragma unroll
    for (int c = 0; c < 4; ++c) mv[a][c] = -INFINITY;

  const float4* src = reinterpret_cast<const float4*>(x + ((size_t)b * 4096 + n0) * 64);
  float4* xs4 = reinterpret_cast<float4*>(xs);

  for (int tile = 0; tile < ntile; ++tile) {
#pragma unroll
    for (int q = 0; q < 4; ++q) xs4[t + 256 * q] = src[(size_t)tile * 1024 + t + 256 * q];
    __syncthreads();
#pragma unroll 4
    for (int n = 0; n < 64; ++n) {
      const float4 vi = *reinterpret_cast<const float4*>(&xs[n * 64 + i0]);
      const float4 vj = *reinterpret_cast<const float4*>(&xs[n * 64 + j0]);
      const float fi[4] = {vi.x, vi.y, vi.z, vi.w};
      const float fj[4] = {vj.x, vj.y, vj.z, vj.w};
#pragma unroll
      for (int a = 0; a < 4; ++a)
#pragma unroll
        for (int c = 0; c < 4; ++c)
          mv[a][c] = fmaxf(mv[a][c], fi[a] * fj[c]);
    }
    __syncthreads();
  }

#pragma unroll
  for (int a = 0; a < 4; ++a)
#pragma unroll
    for (int c = 0; c < 4; ++c)
      xs[(i0 + a) * 64 + (j0 + c)] = mv[a][c];
  __syncthreads();

  float* dst = part + ((size_t)b * G + g) * 4096;
#pragma unroll
  for (int q = 0; q < 16; ++q) dst[t + 256 * q] = xs[t + 256 * q];
}

// ---------------------------------------------------------------------------
// Kernel 2: reduce partial maxima -> pooled A per batch.
// ---------------------------------------------------------------------------
__global__ __launch_bounds__(256) void reduce_kernel(const float* __restrict__ part,
                                                     float* __restrict__ Apool,
                                                     int G) {
  const int b = blockIdx.x, t = threadIdx.x;
#pragma unroll
  for (int u = 0; u < 16; ++u) {
    const int e = t + 256 * u;
    float m = -INFINITY;
    for (int g = 0; g < G; ++g)
      m = fmaxf(m, part[((size_t)b * G + g) * 4096 + e]);
    Apool[(size_t)b * 4096 + e] = m;
  }
}

// ---------------------------------------------------------------------------
// Kernel 3: one-sided Jacobi SVD, one wave64 per batch, columns in registers.
// Thread `lane` owns column `lane` of G (evolving A) and V (rotations).
// No barriers in the sweep loop: all exchange via __shfl (ds_bpermute).
// Both partners derive bitwise-consistent +/-(c,s): tau negates exactly,
// tau==+/-0 tie broken by lane<partner. Output R = sum_j sigma_j^{-1/2} g_j v_j^T
// == U diag(sqrt(s)) V^T, matching the reference SVD path with no sign logic.
// ---------------------------------------------------------------------------
__global__ __launch_bounds__(64, 1) void svd_kernel(const float* __restrict__ Apool,
                                                    float* __restrict__ out) {
  __shared__ __align__(16) float Wl[64 * 68];
  __shared__ __align__(16) float Vl[64 * 68];

  const int b = blockIdx.x;
  const int lane = threadIdx.x;
  const float* A = Apool + (size_t)b * 4096;

  float g[64], v[64], ex[64];

#pragma unroll
  for (int k = 0; k < 64; ++k) {
    g[k] = A[k * 64 + lane];     // coalesced: lane-consecutive
    v[k] = (k == lane) ? 1.0f : 0.0f;
  }

  for (int sweep = 0; sweep < NSWEEP; ++sweep) {
    // refresh tracked column norm (exact) once per sweep
    float a0 = 0, a1 = 0, a2 = 0, a3 = 0;
#pragma unroll
    for (int k = 0; k < 64; k += 4) {
      a0 = fmaf(g[k], g[k], a0);
      a1 = fmaf(g[k + 1], g[k + 1], a1);
      a2 = fmaf(g[k + 2], g[k + 2], a2);
      a3 = fmaf(g[k + 3], g[k + 3], a3);
    }
    float a = (a0 + a1) + (a2 + a3);

    for (int r = 0; r < 63; ++r) {
      // round-robin partner (player 0 fixed, others rotate)
      int partner;
      if (lane == 0) {
        int q = 62 + r; if (q >= 63) q -= 63;
        partner = 1 + q;
      } else {
        int u = lane - 1 - r; if (u < 0) u += 63;
        if (u == 62) partner = 0;
        else { int m = 61 - u + r; if (m >= 63) m -= 63; partner = 1 + m; }
      }

      // exchange partner's G column (64 independent ds_bpermute, pipelined)
#pragma unroll
      for (int k = 0; k < 64; ++k) ex[k] = __shfl(g[k], partner, 64);
      const float bb = __shfl(a, partner, 64);

      float d0 = 0, d1 = 0, d2 = 0, d3 = 0;
#pragma unroll
      for (int k = 0; k < 64; k += 4) {
        d0 = fmaf(g[k], ex[k], d0);
        d1 = fmaf(g[k + 1], ex[k + 1], d1);
        d2 = fmaf(g[k + 2], ex[k + 2], d2);
        d3 = fmaf(g[k + 3], ex[k + 3], d3);
      }
      const float d = (d0 + d1) + (d2 + d3);   // bitwise-identical for both partners

      float c, s;
      if (d != 0.0f) {
        const float tau = (bb - a) * 0.5f / d;  // exactly negated on partner
        float t;
        if (tau == 0.0f) t = (lane < partner) ? 1.0f : -1.0f;  // tie-break
        else t = copysignf(1.0f / (fabsf(tau) + sqrtf(fmaf(tau, tau, 1.0f))), tau);
        c = rsqrtf(fmaf(t, t, 1.0f));           // identical both sides (t^2 equal)
        s = t * c;                               // opposite sign on partner
      } else {
        c = 1.0f; s = 0.0f;
      }
      const float ns = -s;

#pragma unroll
      for (int k = 0; k < 64; ++k) g[k] = fmaf(ns, ex[k], c * g[k]);

      // exchange partner's V column (reuse ex; per-k WAR lets scheduler overlap)
#pragma unroll
      for (int k = 0; k < 64; ++k) ex[k] = __shfl(v[k], partner, 64);
#pragma unroll
      for (int k = 0; k < 64; ++k) v[k] = fmaf(ns, ex[k], c * v[k]);

      // ||g'||^2 = c^2 a + s^2 b - 2 c s d  (exact update, refreshed per sweep)
      a = fmaf(c * c, a, fmaf(s * s, bb, -2.0f * (c * s) * d));
    }
  }

  // ---- W = G * diag(sigma^{-1/2}); R = W V^T ----
  float s0 = 0, s1 = 0, s2 = 0, s3 = 0;
#pragma unroll
  for (int k = 0; k < 64; k += 4) {
    s0 = fmaf(g[k], g[k], s0);
    s1 = fmaf(g[k + 1], g[k + 1], s1);
    s2 = fmaf(g[k + 2], g[k + 2], s2);
    s3 = fmaf(g[k + 3], g[k + 3], s3);
  }
  const float sig2 = (s0 + s1) + (s2 + s3);
  const float sigma = sqrtf(sig2);
  const float coef = (sigma > 1e-30f) ? rsqrtf(sigma) : 0.0f;

#pragma unroll
  for (int k = 0; k < 64; ++k) {
    Wl[k * 68 + lane] = g[k] * coef;   // row k of W, lane-consecutive: conflict-free
    Vl[k * 68 + lane] = v[k];
  }
  __syncthreads();

  // my row of W into registers (reuse g)
#pragma unroll
  for (int j = 0; j < 64; ++j) g[j] = Wl[lane * 68 + j];
  __syncthreads();

  float ssq = 0.0f;
#pragma unroll 4
  for (int i = 0; i < 64; ++i) {
    const float4* vr = reinterpret_cast<const float4*>(Vl + i * 68);  // 272B rows: 16B aligned
    float c0 = 0, c1 = 0, c2 = 0, c3 = 0;
#pragma unroll
    for (int jb = 0; jb < 16; ++jb) {
      const float4 vv = vr[jb];   // broadcast read, conflict-free
      c0 = fmaf(g[4 * jb + 0], vv.x, c0);
      c1 = fmaf(g[4 * jb + 1], vv.y, c1);
      c2 = fmaf(g[4 * jb + 2], vv.z, c2);
      c3 = fmaf(g[4 * jb + 3], vv.w, c3);
    }
    const float acc = (c0 + c1) + (c2 + c3);   // R[lane][i]
    Wl[lane * 68 + i] = acc;                   // own row only: no cross-lane hazard
    ssq = fmaf(acc, acc, ssq);
  }

  // wave-wide reduction of ||R||_F^2
#pragma unroll
  for (int off = 32; off; off >>= 1) ssq += __shfl_xor(ssq, off, 64);
  const float rn = rsqrtf(fmaxf(ssq, 1e-24f));

  __syncthreads();
  float* o = out + (size_t)b * 4096;
#pragma unroll
  for (int q = 0; q < 64; ++q)
    o[q * 64 + lane] = Wl[q * 68 + lane] * rn;   // coalesced store
}

extern "C" void kernel_launch(void* const* d_in, const int* in_sizes, int n_in,
                              void* d_out, int out_size, void* d_ws, size_t ws_size,
                              hipStream_t stream) {
  const float* x = (const float*)d_in[0];
  float* out = (float*)d_out;

  // ws layout: [Apool: 16*4096 f32][part: 16*G*4096 f32]
  int G = 16;
  while (G > 1 && (size_t)(16 + 16 * G) * 4096 * 4 > ws_size) G >>= 1;
  float* Apool = (float*)d_ws;
  float* part = Apool + (size_t)16 * 4096;

  pool_kernel<<<dim3(16 * G), dim3(256), 0, stream>>>(x, part, G);
  reduce_kernel<<<dim3(16), dim3(256), 0, stream>>>(part, Apool, G);
  svd_kernel<<<dim3(16), dim3(64), 0, stream>>>(Apool, out);
}

// Round 3
// 391.555 us; speedup vs baseline: 2.2590x; 1.5981x over previous
//
#include <hip/hip_runtime.h>
#include <math.h>

#define NSWEEP 6

// ---------------------------------------------------------------------------
// Kernel 1: partial max-pooled outer products. Grid = B*G blocks.
// ---------------------------------------------------------------------------
__global__ __launch_bounds__(256) void pool_kernel(const float* __restrict__ x,
                                                   float* __restrict__ part,
                                                   int G) {
  __shared__ float xs[4096];
  const int t = threadIdx.x;
  const int blk = blockIdx.x;
  const int b = blk / G, g = blk % G;
  const int npb = 4096 / G;
  const int ntile = npb >> 6;
  const int n0 = g * npb;
  const int i0 = (t >> 4) * 4;
  const int j0 = (t & 15) * 4;

  float mv[4][4];
#pragma unroll
  for (int a = 0; a < 4; ++a)
#pragma unroll
    for (int c = 0; c < 4; ++c) mv[a][c] = -INFINITY;

  const float4* src = reinterpret_cast<const float4*>(x + ((size_t)b * 4096 + n0) * 64);
  float4* xs4 = reinterpret_cast<float4*>(xs);

  for (int tile = 0; tile < ntile; ++tile) {
#pragma unroll
    for (int q = 0; q < 4; ++q) xs4[t + 256 * q] = src[(size_t)tile * 1024 + t + 256 * q];
    __syncthreads();
#pragma unroll 4
    for (int n = 0; n < 64; ++n) {
      const float4 vi = *reinterpret_cast<const float4*>(&xs[n * 64 + i0]);
      const float4 vj = *reinterpret_cast<const float4*>(&xs[n * 64 + j0]);
      const float fi[4] = {vi.x, vi.y, vi.z, vi.w};
      const float fj[4] = {vj.x, vj.y, vj.z, vj.w};
#pragma unroll
      for (int a = 0; a < 4; ++a)
#pragma unroll
        for (int c = 0; c < 4; ++c)
          mv[a][c] = fmaxf(mv[a][c], fi[a] * fj[c]);
    }
    __syncthreads();
  }

#pragma unroll
  for (int a = 0; a < 4; ++a)
#pragma unroll
    for (int c = 0; c < 4; ++c)
      xs[(i0 + a) * 64 + (j0 + c)] = mv[a][c];
  __syncthreads();

  float* dst = part + ((size_t)b * G + g) * 4096;
#pragma unroll
  for (int q = 0; q < 16; ++q) dst[t + 256 * q] = xs[t + 256 * q];
}

// ---------------------------------------------------------------------------
// Kernel 2: fused max-reduce + 4-wave one-sided Jacobi SVD + reconstruction.
// Waves 0,1 own row-halves of G; waves 2,3 own row-halves of V. One barrier
// per round; all waves re-derive identical (c,s) from shared (a,b,d).
// ---------------------------------------------------------------------------
__global__ __launch_bounds__(256, 1) void svd_kernel(const float* __restrict__ part,
                                                     float* __restrict__ out, int G) {
  __shared__ __align__(16) float Wl[64 * 68];
  __shared__ __align__(16) float Vl[64 * 68];
  __shared__ float dbuf[2][2][64];
  __shared__ float abuf[2][64];
  __shared__ float red[4];

  const int b = blockIdx.x;
  const int t = threadIdx.x;
  const int wave = t >> 6, lane = t & 63;
  const int h = wave & 1;      // row half
  const int isV = wave >> 1;   // 0: G-columns, 1: V-columns

  // ---- fused max-reduce of partials into Wl (stride 68) ----
  const float4* p4 = reinterpret_cast<const float4*>(part) + (size_t)b * G * 1024;
  float4 acc[4];
#pragma unroll
  for (int u = 0; u < 4; ++u) acc[u] = p4[t + 256 * u];
#pragma unroll 2
  for (int g = 1; g < G; ++g) {
#pragma unroll
    for (int u = 0; u < 4; ++u) {
      const float4 v = p4[(size_t)g * 1024 + t + 256 * u];
      acc[u].x = fmaxf(acc[u].x, v.x);
      acc[u].y = fmaxf(acc[u].y, v.y);
      acc[u].z = fmaxf(acc[u].z, v.z);
      acc[u].w = fmaxf(acc[u].w, v.w);
    }
  }
#pragma unroll
  for (int u = 0; u < 4; ++u) {
    const int idx = t + 256 * u;            // float4 index in [0,1024)
    const int i = idx >> 4;                  // row
    const int j = (idx & 15) * 4;            // col base
    *reinterpret_cast<float4*>(&Wl[i * 68 + j]) = acc[u];
  }
  __syncthreads();

  // ---- per-lane column halves in registers ----
  float col[32], ex[32];
  if (!isV) {
#pragma unroll
    for (int k = 0; k < 32; ++k) col[k] = Wl[(h * 32 + k) * 68 + lane];
  } else {
#pragma unroll
    for (int k = 0; k < 32; ++k) col[k] = ((h * 32 + k) == lane) ? 1.0f : 0.0f;
  }

  float a = 0.0f;
  for (int sweep = 0; sweep < NSWEEP; ++sweep) {
    // exact column-norm refresh (G-waves produce halves; everyone tracks a)
    if (!isV) {
      float s0 = 0, s1 = 0, s2 = 0, s3 = 0;
#pragma unroll
      for (int k = 0; k < 32; k += 4) {
        s0 = fmaf(col[k], col[k], s0);
        s1 = fmaf(col[k + 1], col[k + 1], s1);
        s2 = fmaf(col[k + 2], col[k + 2], s2);
        s3 = fmaf(col[k + 3], col[k + 3], s3);
      }
      abuf[h][lane] = (s0 + s1) + (s2 + s3);
    }
    __syncthreads();
    a = abuf[0][lane] + abuf[1][lane];
    // (no barrier needed: next abuf write is a full sweep of barriers away)

    for (int r = 0; r < 63; ++r) {
      // round-robin partner (identical closed form in every wave)
      int partner;
      if (lane == 0) {
        int q = 62 + r; if (q >= 63) q -= 63;
        partner = 1 + q;
      } else {
        int u = lane - 1 - r; if (u < 0) u += 63;
        if (u == 62) partner = 0;
        else { int m = 61 - u + r; if (m >= 63) m -= 63; partner = 1 + m; }
      }

      // exchange partner's column half (32 bpermute, within-wave)
#pragma unroll
      for (int k = 0; k < 32; ++k) ex[k] = __shfl(col[k], partner, 64);
      const float bb = __shfl(a, partner, 64);

      if (!isV) {
        float d0 = 0, d1 = 0, d2 = 0, d3 = 0;
#pragma unroll
        for (int k = 0; k < 32; k += 4) {
          d0 = fmaf(col[k], ex[k], d0);
          d1 = fmaf(col[k + 1], ex[k + 1], d1);
          d2 = fmaf(col[k + 2], ex[k + 2], d2);
          d3 = fmaf(col[k + 3], ex[k + 3], d3);
        }
        dbuf[r & 1][h][lane] = (d0 + d1) + (d2 + d3);
      }
      __syncthreads();
      const float d = dbuf[r & 1][0][lane] + dbuf[r & 1][1][lane];

      float c, s;
      if (d != 0.0f) {
        const float tau = (bb - a) * 0.5f / d;   // exactly negated on partner
        float tt;
        if (tau == 0.0f) tt = (lane < partner) ? 1.0f : -1.0f;  // consistent tie-break
        else tt = copysignf(1.0f / (fabsf(tau) + sqrtf(fmaf(tau, tau, 1.0f))), tau);
        c = rsqrtf(fmaf(tt, tt, 1.0f));          // identical both partners
        s = tt * c;                               // opposite sign on partner
      } else {
        c = 1.0f; s = 0.0f;
      }
      const float ns = -s;
#pragma unroll
      for (int k = 0; k < 32; ++k) col[k] = fmaf(ns, ex[k], c * col[k]);
      // exact rotated-norm update (refreshed each sweep)
      a = fmaf(c * c, a, fmaf(s * s, bb, -2.0f * (c * s) * d));
    }
  }

  // ---- exact sigma, W = G * diag(sigma^{-1/2}) ----
  if (!isV) {
    float s0 = 0, s1 = 0, s2 = 0, s3 = 0;
#pragma unroll
    for (int k = 0; k < 32; k += 4) {
      s0 = fmaf(col[k], col[k], s0);
      s1 = fmaf(col[k + 1], col[k + 1], s1);
      s2 = fmaf(col[k + 2], col[k + 2], s2);
      s3 = fmaf(col[k + 3], col[k + 3], s3);
    }
    abuf[h][lane] = (s0 + s1) + (s2 + s3);
  }
  __syncthreads();
  a = abuf[0][lane] + abuf[1][lane];
  const float sigma = sqrtf(a);
  const float coef = (sigma > 1e-30f) ? rsqrtf(sigma) : 0.0f;

  if (!isV) {
#pragma unroll
    for (int k = 0; k < 32; ++k) Wl[(h * 32 + k) * 68 + lane] = col[k] * coef;
  } else {
#pragma unroll
    for (int k = 0; k < 32; ++k) Vl[(h * 32 + k) * 68 + lane] = col[k];
  }
  __syncthreads();

  // ---- R = W * V^T; each wave computes 16 columns for all 64 rows ----
  float wr[64];
#pragma unroll
  for (int jb = 0; jb < 16; ++jb) {
    const float4 v = *reinterpret_cast<const float4*>(&Wl[lane * 68 + jb * 4]);
    wr[4 * jb] = v.x; wr[4 * jb + 1] = v.y; wr[4 * jb + 2] = v.z; wr[4 * jb + 3] = v.w;
  }
  __syncthreads();   // Wl free for R

  const int j0 = wave * 16;
  float rvals[16];
  float ssq = 0.0f;
#pragma unroll 4
  for (int jj = 0; jj < 16; ++jj) {
    const float4* vr = reinterpret_cast<const float4*>(&Vl[(j0 + jj) * 68]);
    float c0 = 0, c1 = 0, c2 = 0, c3 = 0;
#pragma unroll
    for (int kb = 0; kb < 16; ++kb) {
      const float4 vv = vr[kb];    // broadcast read: conflict-free
      c0 = fmaf(wr[4 * kb], vv.x, c0);
      c1 = fmaf(wr[4 * kb + 1], vv.y, c1);
      c2 = fmaf(wr[4 * kb + 2], vv.z, c2);
      c3 = fmaf(wr[4 * kb + 3], vv.w, c3);
    }
    const float accv = (c0 + c1) + (c2 + c3);   // R[lane][j0+jj]
    rvals[jj] = accv;
    ssq = fmaf(accv, accv, ssq);
  }
#pragma unroll
  for (int jj = 0; jj < 4; ++jj)
    *reinterpret_cast<float4*>(&Wl[lane * 68 + j0 + 4 * jj]) =
        make_float4(rvals[4 * jj], rvals[4 * jj + 1], rvals[4 * jj + 2], rvals[4 * jj + 3]);

  // ---- ||R||_F^2 reduction across block ----
#pragma unroll
  for (int off = 32; off; off >>= 1) ssq += __shfl_xor(ssq, off, 64);
  if (lane == 0) red[wave] = ssq;
  __syncthreads();
  const float rn = rsqrtf(fmaxf(red[0] + red[1] + red[2] + red[3], 1e-24f));

#pragma unroll
  for (int u = 0; u < 16; ++u) {
    const int e = t + 256 * u;
    out[(size_t)b * 4096 + e] = Wl[(e >> 6) * 68 + (e & 63)] * rn;   // coalesced
  }
}

extern "C" void kernel_launch(void* const* d_in, const int* in_sizes, int n_in,
                              void* d_out, int out_size, void* d_ws, size_t ws_size,
                              hipStream_t stream) {
  const float* x = (const float*)d_in[0];
  float* out = (float*)d_out;
  float* part = (float*)d_ws;

  int G = 32;
  while (G > 1 && (size_t)16 * G * 4096 * 4 > ws_size) G >>= 1;

  pool_kernel<<<dim3(16 * G), dim3(256), 0, stream>>>(x, part, G);
  svd_kernel<<<dim3(16), dim3(256), 0, stream>>>(part, out, G);
}